// Round 1
// baseline (747.851 us; speedup 1.0000x reference)
//
#include <hip/hip_runtime.h>

// ---------------------------------------------------------------------------
// Attention with log-prob bias + mask, outputs (out, p_attn), fp32 I/O.
// B=2, H=8, N=2048, D=64.  Memory-bound on p/mask reads + p_attn write
// (~800 MB compulsory -> ~127us floor @ 6.3 TB/s).  bf16 MFMA for QK^T and PV.
// ---------------------------------------------------------------------------

typedef float  f4v   __attribute__((ext_vector_type(4)));
typedef int    i4v   __attribute__((ext_vector_type(4)));
typedef __bf16 bf16x8 __attribute__((ext_vector_type(8)));
typedef unsigned short us8 __attribute__((ext_vector_type(8)));
typedef unsigned short us4 __attribute__((ext_vector_type(4)));
typedef unsigned int   u4v __attribute__((ext_vector_type(4)));

#define MFMA16(a,b,c) __builtin_amdgcn_mfma_f32_16x16x32_bf16((a),(b),(c),0,0,0)

static __device__ __forceinline__ unsigned short f2bf(float f){
  unsigned u = __builtin_bit_cast(unsigned, f);
  u += 0x7fffu + ((u >> 16) & 1u);          // RNE to bf16 (inputs are finite)
  return (unsigned short)(u >> 16);
}
static __device__ __forceinline__ bf16x8 ldg8(const unsigned short* p){
  u4v v = *(const u4v*)p;                    // 16B aligned by construction
  return __builtin_bit_cast(bf16x8, v);
}

// ---- prep: Q*0.125 and K to bf16 (row-major, same layout as fp32 source) ---
__global__ void prep_qk(const float* __restrict__ Q, const float* __restrict__ K,
                        unsigned short* __restrict__ Qb, unsigned short* __restrict__ Kb){
  int i = blockIdx.x * 256 + threadIdx.x;    // 2048 blocks -> covers 2,097,152 elems
  int base = i * 4;
  f4v q = *(const f4v*)(Q + base);
  f4v k = *(const f4v*)(K + base);
  us4 qo, ko;
#pragma unroll
  for(int j=0;j<4;j++){ qo[j] = f2bf(q[j] * 0.125f); ko[j] = f2bf(k[j]); }
  *(us4*)(Qb + base) = qo;
  *(us4*)(Kb + base) = ko;
}

// ---- prep: V -> bf16 transposed Vt[bh][d][n]  (B-fragment friendly) --------
__global__ void prep_vt(const float* __restrict__ V, unsigned short* __restrict__ Vt){
  int t   = blockIdx.x * 256 + threadIdx.x;  // 1024 blocks -> 262,144 threads
  int bh  = t >> 14;
  int rem = t & 16383;
  int d   = rem >> 8;
  int n0  = (rem & 255) * 8;
  const float* src = V + (((long)bh*2048 + n0) * 64 + d);
  us8 o;
#pragma unroll
  for(int j=0;j<8;j++) o[j] = f2bf(src[j*64]);
  *(us8*)(Vt + ((long)(bh*64 + d)) * 2048 + n0) = o;
}

// ---- main fused kernel -----------------------------------------------------
// block = 256 threads (4 waves). One block: 16 q-rows of one (b,h).
// wave w owns keys [w*512, (w+1)*512).  s' kept in 128 fp32 regs per lane.
__global__ __launch_bounds__(256, 2) void attn_main(
    const float* __restrict__ P, const int* __restrict__ M,
    const unsigned short* __restrict__ Qb, const unsigned short* __restrict__ Kb,
    const unsigned short* __restrict__ Vt,
    float* __restrict__ out_o, float* __restrict__ out_p){

  __shared__ float stage[4*2*528];   // per-wave double-buffered 16x32 (stride 33) C->A staging
  __shared__ float wred[2][4][16];   // cross-wave max/sum
  __shared__ float obuf[4][16][64];  // O partial sums

  const int tid  = threadIdx.x;
  const int w    = tid >> 6;
  const int lane = tid & 63;
  const int m    = lane & 15;        // A-layout row / C-layout col
  const int q    = lane >> 4;        // quad
  const int bidx = blockIdx.x;
  // XCD-swizzle: bidx%8 -> XCD; heads {2x,2x+1} pinned per XCD for K/V L2 reuse
  const int bh = ((bidx & 7) << 1) | ((bidx >> 3) & 1);
  const int qt = bidx >> 4;
  const int q0 = qt << 4;
  const int wbase = w << 9;

  const long  rowQ  = (long)bh*2048 + q0 + m;   // this lane's global q-row (A-layout)
  const long  pbase = rowQ * 2048;
  const unsigned short* Qrow = Qb + rowQ * 64;
  const bf16x8 qf0 = ldg8(Qrow + q*8);          // A[m][k=8q+j], d 0..31
  const bf16x8 qf1 = ldg8(Qrow + 32 + q*8);     // d 32..63
  const unsigned short* Kbh = Kb + ((long)bh << 17);   // 2048*64
  const unsigned short* Vbh = Vt + ((long)bh << 17);

  float sreg[16][8];                 // scores for (row m) x (cols wbase+32c+8q+j)
  float vmax = -3.0e38f;
  float* st0 = stage + w * 1056;

  // ---------------- phase A: S = QK^T/8 + log(p+1e-12), mask ---------------
#pragma unroll
  for(int c=0;c<16;c++){
    float* st = st0 + (c & 1) * 528;
    const int k0 = wbase + c*32;
    const unsigned short* Kp = Kbh + (long)(k0 + m)*64 + q*8;
    bf16x8 kf00 = ldg8(Kp);                 // B[k=d 0..31][n=key m], keys k0+0..15
    bf16x8 kf01 = ldg8(Kp + 32);            // d 32..63
    bf16x8 kf10 = ldg8(Kp + 16*64);         // keys k0+16..31
    bf16x8 kf11 = ldg8(Kp + 16*64 + 32);
    const float* pp = P + pbase + k0 + q*8;
    f4v pv0 = *(const f4v*)pp;
    f4v pv1 = *(const f4v*)(pp + 4);
    const int* mp = M + pbase + k0 + q*8;
    i4v mv0 = *(const i4v*)mp;
    i4v mv1 = *(const i4v*)(mp + 4);

    f4v acc0 = {0.f,0.f,0.f,0.f}, acc1 = {0.f,0.f,0.f,0.f};
    acc0 = MFMA16(qf0, kf00, acc0);
    acc0 = MFMA16(qf1, kf01, acc0);
    acc1 = MFMA16(qf0, kf10, acc1);
    acc1 = MFMA16(qf1, kf11, acc1);

    // C-layout (row=4q+r, col=16t+m) -> LDS (stride 33, <=4-way banks on write)
#pragma unroll
    for(int r=0;r<4;r++){
      st[(4*q + r)*33 + m]      = acc0[r];
      st[(4*q + r)*33 + 16 + m] = acc1[r];
    }
    float sv[8];
#pragma unroll
    for(int j=0;j<8;j++) sv[j] = st[m*33 + q*8 + j];   // A-layout readback (2-way, free)

#pragma unroll
    for(int j=0;j<8;j++){
      float pj = (j < 4) ? pv0[j] : pv1[j-4];
      int   mj = (j < 4) ? mv0[j] : mv1[j-4];
      float s  = sv[j] + __logf(pj + 1e-12f);
      s = (mj == 0) ? -1.0e9f : s;
      sreg[c][j] = s;
      vmax = fmaxf(vmax, s);
    }
  }

  // ---------------- row max (quad shuffle + cross-wave LDS) ----------------
  vmax = fmaxf(vmax, __shfl_xor(vmax, 16));
  vmax = fmaxf(vmax, __shfl_xor(vmax, 32));
  if(lane < 16) wred[0][w][lane] = vmax;
  __syncthreads();
  const float mrow = fmaxf(fmaxf(wred[0][0][m], wred[0][1][m]),
                           fmaxf(wred[0][2][m], wred[0][3][m]));

  // ---------------- phase C1: e = exp(s-m), row sum ------------------------
  float vsum = 0.f;
#pragma unroll
  for(int c=0;c<16;c++){
#pragma unroll
    for(int j=0;j<8;j++){
      float e = __expf(sreg[c][j] - mrow);
      sreg[c][j] = e;
      vsum += e;
    }
  }
  vsum += __shfl_xor(vsum, 16);
  vsum += __shfl_xor(vsum, 32);
  if(lane < 16) wred[1][w][lane] = vsum;
  __syncthreads();
  const float lsum = wred[1][0][m] + wred[1][1][m] + wred[1][2][m] + wred[1][3][m];
  const float rl = 1.0f / lsum;

  // ---------------- phase C2: write p_attn, O += P*V -----------------------
  f4v o0={0.f,0.f,0.f,0.f}, o1={0.f,0.f,0.f,0.f}, o2={0.f,0.f,0.f,0.f}, o3={0.f,0.f,0.f,0.f};
#pragma unroll
  for(int c=0;c<16;c++){
    const int k0 = wbase + c*32;
    f4v w0, w1; us8 pb;
#pragma unroll
    for(int j=0;j<8;j++){
      float pr = sreg[c][j] * rl;
      if(j < 4) w0[j] = pr; else w1[j-4] = pr;
      pb[j] = f2bf(pr);
    }
    float* op = out_p + pbase + k0 + q*8;
    *(f4v*)op       = w0;
    *(f4v*)(op + 4) = w1;
    bf16x8 af = __builtin_bit_cast(bf16x8, pb);        // A[m][k=8q+j] = P row-frag
    const unsigned short* Vp = Vbh + (long)m*2048 + k0 + q*8;  // Vt[d=n0*16+m][key]
    o0 = MFMA16(af, ldg8(Vp),           o0);
    o1 = MFMA16(af, ldg8(Vp + 16*2048), o1);
    o2 = MFMA16(af, ldg8(Vp + 32*2048), o2);
    o3 = MFMA16(af, ldg8(Vp + 48*2048), o3);
  }

  // ---------------- O: cross-wave sum + store ------------------------------
#pragma unroll
  for(int r=0;r<4;r++){
    obuf[w][4*q + r][m]      = o0[r];
    obuf[w][4*q + r][16 + m] = o1[r];
    obuf[w][4*q + r][32 + m] = o2[r];
    obuf[w][4*q + r][48 + m] = o3[r];
  }
  __syncthreads();
  const int row = tid >> 4, cg = (tid & 15) << 2;
  f4v a0 = *(const f4v*)&obuf[0][row][cg];
  f4v a1 = *(const f4v*)&obuf[1][row][cg];
  f4v a2 = *(const f4v*)&obuf[2][row][cg];
  f4v a3 = *(const f4v*)&obuf[3][row][cg];
  f4v s = a0 + a1 + a2 + a3;
  *(f4v*)(out_o + ((long)bh*2048 + q0 + row)*64 + cg) = s;
}

// ---------------------------------------------------------------------------
extern "C" void kernel_launch(void* const* d_in, const int* in_sizes, int n_in,
                              void* d_out, int out_size, void* d_ws, size_t ws_size,
                              hipStream_t stream){
  const float* Q = (const float*)d_in[0];
  const float* K = (const float*)d_in[1];
  const float* V = (const float*)d_in[2];
  const int*   M = (const int*)  d_in[3];
  const float* P = (const float*)d_in[4];

  float* out_o = (float*)d_out;                       // [2,8,2048,64]
  float* out_p = out_o + (size_t)2*8*2048*64;         // [2,8,2048,2048]

  unsigned short* Qb = (unsigned short*)d_ws;         // 4MB
  unsigned short* Kb = Qb + (size_t)2*8*2048*64;      // 4MB
  unsigned short* Vt = Kb + (size_t)2*8*2048*64;      // 4MB (transposed)

  prep_qk<<<2048, 256, 0, stream>>>(Q, K, Qb, Kb);
  prep_vt<<<1024, 256, 0, stream>>>(V, Vt);
  attn_main<<<2048, 256, 0, stream>>>(P, M, Qb, Kb, Vt, out_o, out_p);
}